// Round 3
// baseline (162.493 us; speedup 1.0000x reference)
//
#include <hip/hip_runtime.h>

#define BLK 128            // threads per block (2 waves)
#define LS  32             // timesteps per thread-chunk
#define SPB (BLK*LS)       // timesteps per block = 4096

// ws float offsets: [0:16) M, [16:24) N, [24+16k) SK[k]=M^(32*2^k) k=0..7,
// [152+16k) GK[k]=M^(4096*2^k) k=0..8, [320..322) int counters, [336+) aggregates
#define WS_M   0
#define WS_N   16
#define WS_SK  24
#define WS_GK  152
#define WS_CNT 320
#define WS_AGG 336

// ---------- affine step macro (row-major M[16], N[8]) ----------
#define STEP4(Mx,Nx, s0,s1,s2,s3, ux,uy, n0,n1,n2,n3)                                              \
  n0 = fmaf(Mx[0],s0,  fmaf(Mx[1],s1,  fmaf(Mx[2],s2,  fmaf(Mx[3],s3,  fmaf(Nx[0],ux, Nx[1]*uy))))); \
  n1 = fmaf(Mx[4],s0,  fmaf(Mx[5],s1,  fmaf(Mx[6],s2,  fmaf(Mx[7],s3,  fmaf(Nx[2],ux, Nx[3]*uy))))); \
  n2 = fmaf(Mx[8],s0,  fmaf(Mx[9],s1,  fmaf(Mx[10],s2, fmaf(Mx[11],s3, fmaf(Nx[4],ux, Nx[5]*uy))))); \
  n3 = fmaf(Mx[12],s0, fmaf(Mx[13],s1, fmaf(Mx[14],s2, fmaf(Mx[15],s3, fmaf(Nx[6],ux, Nx[7]*uy)))));

__device__ __forceinline__ float4 aff_apply(const float* Mx, float4 l, float4 c) {
  float4 r;
  r.x = fmaf(Mx[0],l.x,  fmaf(Mx[1],l.y,  fmaf(Mx[2],l.z,  fmaf(Mx[3],l.w,  c.x))));
  r.y = fmaf(Mx[4],l.x,  fmaf(Mx[5],l.y,  fmaf(Mx[6],l.z,  fmaf(Mx[7],l.w,  c.y))));
  r.z = fmaf(Mx[8],l.x,  fmaf(Mx[9],l.y,  fmaf(Mx[10],l.z, fmaf(Mx[11],l.w, c.z))));
  r.w = fmaf(Mx[12],l.x, fmaf(Mx[13],l.y, fmaf(Mx[14],l.z, fmaf(Mx[15],l.w, c.w))));
  return r;
}

__device__ __forceinline__ float4 matvec(const float* Mx, float4 v) {
  return aff_apply(Mx, v, make_float4(0.f, 0.f, 0.f, 0.f));
}

// ---------- setup: build discrete-time (M, N) and powers in fp64 ----------
__device__ __forceinline__ void mm4d(const double* X, const double* Y, double* Z) {
  for (int i = 0; i < 4; ++i)
    for (int j = 0; j < 4; ++j) {
      double s = 0.0;
      for (int l = 0; l < 4; ++l) s += X[i*4+l] * Y[l*4+j];
      Z[i*4+j] = s;
    }
}

__global__ void k_setup(const float* __restrict__ cin, const float* __restrict__ min_,
                        const float* __restrict__ kin, const float* __restrict__ dtin,
                        float* __restrict__ ws) {
  double c1 = cin[0], c2 = cin[1], c3 = cin[2];
  double m1 = min_[0], m2 = min_[1];
  double k1 = kin[0], k2 = kin[1], k3 = kin[2];
  double h  = dtin[0];

  double A[16] = { 0.0, 1.0, 0.0, 0.0,
                  -(k1+k2)/m1, -(c1+c2)/m1,  k2/m1,  c2/m1,
                   0.0, 0.0, 0.0, 1.0,
                   k2/m2,  c2/m2, -(k3+k2)/m2, -(c3+c2)/m2 };

  double Q[16], R[16], S[16], M[16], tmp[16];
  for (int i = 0; i < 16; ++i) Q[i] = ((i % 5 == 0) ? 1.0 : 0.0) + (h/4.0)*A[i];
  mm4d(A, Q, tmp);
  for (int i = 0; i < 16; ++i) R[i] = ((i % 5 == 0) ? 1.0 : 0.0) + (h/3.0)*tmp[i];
  mm4d(A, R, tmp);
  for (int i = 0; i < 16; ++i) S[i] = ((i % 5 == 0) ? 1.0 : 0.0) + (h/2.0)*tmp[i];
  mm4d(A, S, tmp);
  for (int i = 0; i < 16; ++i) M[i] = ((i % 5 == 0) ? 1.0 : 0.0) + h*tmp[i];

  double N[8];
  for (int i = 0; i < 4; ++i) {
    N[2*i+0] = h * S[i*4+1] / m1;
    N[2*i+1] = h * S[i*4+3] / m2;
  }

  for (int i = 0; i < 16; ++i) ws[WS_M+i] = (float)M[i];
  for (int i = 0; i < 8;  ++i) ws[WS_N+i] = (float)N[i];

  // P = M^32
  double P[16]; for (int i = 0; i < 16; ++i) P[i] = M[i];
  for (int r = 0; r < 5; ++r) { mm4d(P, P, tmp); for (int i = 0; i < 16; ++i) P[i] = tmp[i]; }

  // SK[k] = M^(32*2^k), k=0..7
  for (int i = 0; i < 16; ++i) ws[WS_SK+i] = (float)P[i];
  for (int k = 1; k < 8; ++k) {
    mm4d(P, P, tmp); for (int i = 0; i < 16; ++i) P[i] = tmp[i];
    for (int i = 0; i < 16; ++i) ws[WS_SK+16*k+i] = (float)P[i];
  }
  // now P = M^4096. GK[k] = M^(4096*2^k), k=0..8
  for (int i = 0; i < 16; ++i) ws[WS_GK+i] = (float)P[i];
  for (int k = 1; k < 9; ++k) {
    mm4d(P, P, tmp); for (int i = 0; i < 16; ++i) P[i] = tmp[i];
    for (int i = 0; i < 16; ++i) ws[WS_GK+16*k+i] = (float)P[i];
  }

  // zero grid-barrier counters (ws is poisoned 0xAA before every call)
  int* cnt = (int*)(ws + WS_CNT);
  cnt[0] = 0;
  cnt[1] = 0;
}

// ---------- fused: offsets + block scan + grid barrier + mid scan + replay ----------
__launch_bounds__(BLK)
__global__ void k_fused(const float4* __restrict__ u4, float* __restrict__ ws,
                        const float* __restrict__ x0in, float4* __restrict__ out4,
                        int T2, int nblk) {
  __shared__ float2 tile[BLK * 33];   // block's 4096 u samples (+pad); reused for y
  __shared__ float4 S1[BLK];          // in-block inclusive prefix offsets
  __shared__ float  SKs[8*16];
  __shared__ float  GKs[9*16];
  __shared__ float4 MA[512];          // mid-scan ping
  __shared__ float4 MB[512];          // mid-scan pong
  __shared__ float4 Xsh;              // this block's start state

  const int tid   = threadIdx.x;
  const int bid   = blockIdx.x;
  const int base2 = bid * SPB;

  int*    cnt1 = (int*)(ws + WS_CNT);
  int*    cnt2 = (int*)(ws + WS_CNT) + 1;
  float4* agg  = (float4*)(ws + WS_AGG);

  float Mm[16], Nn[8];
  #pragma unroll
  for (int i = 0; i < 16; ++i) Mm[i] = ws[WS_M+i];
  #pragma unroll
  for (int i = 0; i < 8;  ++i) Nn[i] = ws[WS_N+i];
  if (tid < 128) SKs[tid] = ws[WS_SK + tid];
  if (tid < 16)  { GKs[tid] = ws[WS_GK + tid]; GKs[tid+16] = ws[WS_GK + tid + 16]; }
  if (tid >= 16 && tid < 128) GKs[tid + 16] = ws[WS_GK + tid + 16];  // fills [32:144)

  // ---- stage u coalesced into LDS (zeros past T) ----
  #pragma unroll
  for (int kk = 0; kk < LS/2; ++kk) {
    int idx4 = tid + kk*BLK;
    int p0 = base2 + 2*idx4;
    float4 v = make_float4(0.f, 0.f, 0.f, 0.f);
    if (p0 < T2) v = u4[(base2 >> 1) + idx4];
    int l = 2*idx4, r = l >> 5, e = l & 31;
    tile[r*33 + e]     = make_float2(v.x, v.y);
    tile[r*33 + e + 1] = make_float2(v.z, v.w);
  }
  __syncthreads();

  // ---- per-thread chunk offset over LS steps (from zero state) ----
  float b0 = 0.f, b1 = 0.f, b2 = 0.f, b3 = 0.f;
  #pragma unroll
  for (int j = 0; j < LS; ++j) {
    float2 uu = tile[tid*33 + j];
    float n0, n1, n2, n3;
    STEP4(Mm, Nn, b0, b1, b2, b3, uu.x, uu.y, n0, n1, n2, n3);
    b0 = n0; b1 = n1; b2 = n2; b3 = n3;
  }
  S1[tid] = make_float4(b0, b1, b2, b3);
  __syncthreads();

  // ---- in-block Hillis-Steele over 128 chunk offsets ----
  #pragma unroll
  for (int k = 0; k < 7; ++k) {
    int off = 1 << k;
    float4 l, c;
    bool act = (tid >= off);
    if (act) { l = S1[tid - off]; c = S1[tid]; }
    __syncthreads();
    if (act) S1[tid] = aff_apply(&SKs[16*k], l, c);
    __syncthreads();
  }

  // ---- publish block aggregate (release) ----
  if (tid == BLK-1) {
    agg[bid] = S1[BLK-1];
    __threadfence();
    __hip_atomic_fetch_add(cnt1, 1, __ATOMIC_RELEASE, __HIP_MEMORY_SCOPE_AGENT);
  }

  // ---- block 0: mid scan of [x0, agg_0..agg_{nblk-1}] once all published ----
  if (bid == 0) {
    if (tid == 0) {
      while (__hip_atomic_load(cnt1, __ATOMIC_ACQUIRE, __HIP_MEMORY_SCOPE_AGENT) < nblk)
        __builtin_amdgcn_s_sleep(2);
    }
    __syncthreads();

    const int n = nblk + 1;
    #pragma unroll
    for (int j = 0; j < 4; ++j) {
      int i = tid + BLK*j;
      if (i < n) MA[i] = (i == 0) ? make_float4(x0in[0], x0in[1], x0in[2], x0in[3])
                                  : agg[i-1];
    }
    __syncthreads();

    float4* Aa = MA; float4* Bb = MB;
    for (int k = 0; k < 9; ++k) {
      int off = 1 << k;
      if (off >= n) break;
      #pragma unroll
      for (int j = 0; j < 4; ++j) {
        int i = tid + BLK*j;
        if (i < n) {
          float4 v = Aa[i];
          if (i >= off) v = aff_apply(&GKs[16*k], Aa[i-off], v);
          Bb[i] = v;
        }
      }
      __syncthreads();
      float4* t = Aa; Aa = Bb; Bb = t;
    }

    #pragma unroll
    for (int j = 0; j < 4; ++j) {
      int i = tid + BLK*j;
      if (i < nblk) agg[i] = Aa[i];     // state at start of block i (in-place)
    }
    __syncthreads();
    if (tid == 0) {
      __threadfence();
      __hip_atomic_store(cnt2, 1, __ATOMIC_RELEASE, __HIP_MEMORY_SCOPE_AGENT);
    }
  }

  // ---- wait for mid results; fetch my block-start state ----
  if (tid == 0) {
    while (__hip_atomic_load(cnt2, __ATOMIC_ACQUIRE, __HIP_MEMORY_SCOPE_AGENT) < 1)
      __builtin_amdgcn_s_sleep(2);
    Xsh = agg[bid];
  }
  __syncthreads();

  // ---- per-thread start state: M^(32*tid)·X + exclusive in-block prefix ----
  float4 v = Xsh;
  #pragma unroll
  for (int k = 0; k < 7; ++k)
    if (tid & (1 << k)) v = matvec(&SKs[16*k], v);   // powers of M commute
  float4 p = (tid > 0) ? S1[tid-1] : make_float4(0.f, 0.f, 0.f, 0.f);
  float x0 = v.x + p.x, x1 = v.y + p.y, x2 = v.z + p.z, x3 = v.w + p.w;

  // ---- replay LS steps, emit (z1, z2) over consumed u ----
  #pragma unroll
  for (int j = 0; j < LS; ++j) {
    float2 uu = tile[tid*33 + j];
    float n0, n1, n2, n3;
    STEP4(Mm, Nn, x0, x1, x2, x3, uu.x, uu.y, n0, n1, n2, n3);
    x0 = n0; x1 = n1; x2 = n2; x3 = n3;
    tile[tid*33 + j] = make_float2(x0, x2);
  }
  __syncthreads();

  #pragma unroll
  for (int kk = 0; kk < LS/2; ++kk) {
    int idx4 = tid + kk*BLK;
    int p0 = base2 + 2*idx4;
    if (p0 < T2) {
      int l = 2*idx4, r = l >> 5, e = l & 31;
      float2 a = tile[r*33 + e];
      float2 b = tile[r*33 + e + 1];
      out4[(base2 >> 1) + idx4] = make_float4(a.x, a.y, b.x, b.y);
    }
  }
}

extern "C" void kernel_launch(void* const* d_in, const int* in_sizes, int n_in,
                              void* d_out, int out_size, void* d_ws, size_t ws_size,
                              hipStream_t stream) {
  const float* u   = (const float*)d_in[0];
  const float* x0  = (const float*)d_in[1];
  const float* cc  = (const float*)d_in[2];
  const float* mm  = (const float*)d_in[3];
  const float* kk  = (const float*)d_in[4];
  const float* dt  = (const float*)d_in[5];

  const int T2   = in_sizes[0] / 2;            // timesteps
  const int nblk = (T2 + SPB - 1) / SPB;       // 489 for T=2e6; nblk+1 <= 512 required
                                               // (489 blocks co-resident: 3 blocks/CU by LDS)
  float* ws = (float*)d_ws;

  k_setup<<<1, 1, 0, stream>>>(cc, mm, kk, dt, ws);
  k_fused<<<nblk, BLK, 0, stream>>>((const float4*)u, ws, x0, (float4*)d_out, T2, nblk);
}

// Round 4
// 98.512 us; speedup vs baseline: 1.6495x; 1.6495x over previous
//
#include <hip/hip_runtime.h>

#define BLK 256            // threads per block (4 waves)
#define LS  16             // timesteps per thread-chunk
#define SPB (BLK*LS)       // timesteps per block = 4096
#define STR (LS+1)         // plane stride 17: bank=(17t+j)%32, gcd(17,32)=1 -> conflict-free

// ws float offsets: [0:16) M, [16:24) N, [24+16k) SK[k]=M^(16*2^k) k=0..7,
// [152+16k) GK[k]=M^(4096*2^k) k=0..8, [304) agg (512 float4), [2352) S1 buf
#define WS_M   0
#define WS_N   16
#define WS_SK  24
#define WS_GK  152
#define WS_AGG 304
#define WS_S1  2352

// ---------- affine step macro (row-major M[16], N[8]) ----------
#define STEP4(Mx,Nx, s0,s1,s2,s3, ux,uy, n0,n1,n2,n3)                                              \
  n0 = fmaf(Mx[0],s0,  fmaf(Mx[1],s1,  fmaf(Mx[2],s2,  fmaf(Mx[3],s3,  fmaf(Nx[0],ux, Nx[1]*uy))))); \
  n1 = fmaf(Mx[4],s0,  fmaf(Mx[5],s1,  fmaf(Mx[6],s2,  fmaf(Mx[7],s3,  fmaf(Nx[2],ux, Nx[3]*uy))))); \
  n2 = fmaf(Mx[8],s0,  fmaf(Mx[9],s1,  fmaf(Mx[10],s2, fmaf(Mx[11],s3, fmaf(Nx[4],ux, Nx[5]*uy))))); \
  n3 = fmaf(Mx[12],s0, fmaf(Mx[13],s1, fmaf(Mx[14],s2, fmaf(Mx[15],s3, fmaf(Nx[6],ux, Nx[7]*uy)))));

__device__ __forceinline__ float4 aff_apply(const float* Mx, float4 l, float4 c) {
  float4 r;
  r.x = fmaf(Mx[0],l.x,  fmaf(Mx[1],l.y,  fmaf(Mx[2],l.z,  fmaf(Mx[3],l.w,  c.x))));
  r.y = fmaf(Mx[4],l.x,  fmaf(Mx[5],l.y,  fmaf(Mx[6],l.z,  fmaf(Mx[7],l.w,  c.y))));
  r.z = fmaf(Mx[8],l.x,  fmaf(Mx[9],l.y,  fmaf(Mx[10],l.z, fmaf(Mx[11],l.w, c.z))));
  r.w = fmaf(Mx[12],l.x, fmaf(Mx[13],l.y, fmaf(Mx[14],l.z, fmaf(Mx[15],l.w, c.w))));
  return r;
}

__device__ __forceinline__ float4 matvec(const float* Mx, float4 v) {
  return aff_apply(Mx, v, make_float4(0.f, 0.f, 0.f, 0.f));
}

// ---------- setup: build discrete-time (M, N) and powers in fp64 ----------
__device__ __forceinline__ void mm4d(const double* X, const double* Y, double* Z) {
  for (int i = 0; i < 4; ++i)
    for (int j = 0; j < 4; ++j) {
      double s = 0.0;
      for (int l = 0; l < 4; ++l) s += X[i*4+l] * Y[l*4+j];
      Z[i*4+j] = s;
    }
}

__global__ void k_setup(const float* __restrict__ cin, const float* __restrict__ min_,
                        const float* __restrict__ kin, const float* __restrict__ dtin,
                        float* __restrict__ ws) {
  double c1 = cin[0], c2 = cin[1], c3 = cin[2];
  double m1 = min_[0], m2 = min_[1];
  double k1 = kin[0], k2 = kin[1], k3 = kin[2];
  double h  = dtin[0];

  double A[16] = { 0.0, 1.0, 0.0, 0.0,
                  -(k1+k2)/m1, -(c1+c2)/m1,  k2/m1,  c2/m1,
                   0.0, 0.0, 0.0, 1.0,
                   k2/m2,  c2/m2, -(k3+k2)/m2, -(c3+c2)/m2 };

  double Q[16], R[16], S[16], M[16], tmp[16];
  for (int i = 0; i < 16; ++i) Q[i] = ((i % 5 == 0) ? 1.0 : 0.0) + (h/4.0)*A[i];
  mm4d(A, Q, tmp);
  for (int i = 0; i < 16; ++i) R[i] = ((i % 5 == 0) ? 1.0 : 0.0) + (h/3.0)*tmp[i];
  mm4d(A, R, tmp);
  for (int i = 0; i < 16; ++i) S[i] = ((i % 5 == 0) ? 1.0 : 0.0) + (h/2.0)*tmp[i];
  mm4d(A, S, tmp);
  for (int i = 0; i < 16; ++i) M[i] = ((i % 5 == 0) ? 1.0 : 0.0) + h*tmp[i];

  double N[8];
  for (int i = 0; i < 4; ++i) {
    N[2*i+0] = h * S[i*4+1] / m1;
    N[2*i+1] = h * S[i*4+3] / m2;
  }

  for (int i = 0; i < 16; ++i) ws[WS_M+i] = (float)M[i];
  for (int i = 0; i < 8;  ++i) ws[WS_N+i] = (float)N[i];

  // P = M^16 (4 squarings)
  double P[16]; for (int i = 0; i < 16; ++i) P[i] = M[i];
  for (int r = 0; r < 4; ++r) { mm4d(P, P, tmp); for (int i = 0; i < 16; ++i) P[i] = tmp[i]; }

  // SK[k] = M^(16*2^k), k=0..7
  for (int i = 0; i < 16; ++i) ws[WS_SK+i] = (float)P[i];
  for (int k = 1; k < 8; ++k) {
    mm4d(P, P, tmp); for (int i = 0; i < 16; ++i) P[i] = tmp[i];
    for (int i = 0; i < 16; ++i) ws[WS_SK+16*k+i] = (float)P[i];
  }
  // P = M^2048 here; one more squaring -> M^4096. GK[k] = M^(4096*2^k), k=0..8
  mm4d(P, P, tmp); for (int i = 0; i < 16; ++i) P[i] = tmp[i];
  for (int i = 0; i < 16; ++i) ws[WS_GK+i] = (float)P[i];
  for (int k = 1; k < 9; ++k) {
    mm4d(P, P, tmp); for (int i = 0; i < 16; ++i) P[i] = tmp[i];
    for (int i = 0; i < 16; ++i) ws[WS_GK+16*k+i] = (float)P[i];
  }
}

// ---------- pass1: chunk offsets + in-block inclusive scan -> S1 global + aggregate ----------
__launch_bounds__(BLK)
__global__ void k_pass1(const float4* __restrict__ u4, const float* __restrict__ ws,
                        float4* __restrict__ s1out, float4* __restrict__ agg, int T2) {
  __shared__ float  uxp[BLK*STR];     // u channel-0 plane, conflict-free stride 17
  __shared__ float  uyp[BLK*STR];     // u channel-1 plane
  __shared__ float4 S1[BLK];
  __shared__ float  SKs[8*16];
  const int tid   = threadIdx.x;
  const int bid   = blockIdx.x;
  const int base2 = bid * SPB;

  float Mm[16], Nn[8];
  #pragma unroll
  for (int i = 0; i < 16; ++i) Mm[i] = ws[WS_M+i];
  #pragma unroll
  for (int i = 0; i < 8;  ++i) Nn[i] = ws[WS_N+i];
  if (tid < 128) SKs[tid] = ws[WS_SK + tid];

  // stage u coalesced into split planes (zeros past T)
  #pragma unroll
  for (int kk = 0; kk < SPB/2/BLK; ++kk) {     // 8 float4 per thread
    int idx4 = tid + kk*BLK;
    int s0 = 2*idx4;                           // timestep of (v.x,v.y)
    float4 v = make_float4(0.f, 0.f, 0.f, 0.f);
    if (base2 + s0 < T2) v = u4[(base2 >> 1) + idx4];
    int t0 = s0 >> 4, j0 = s0 & 15;
    int t1 = (s0+1) >> 4, j1 = (s0+1) & 15;
    uxp[t0*STR + j0] = v.x;  uyp[t0*STR + j0] = v.y;
    uxp[t1*STR + j1] = v.z;  uyp[t1*STR + j1] = v.w;
  }
  __syncthreads();

  // per-thread chunk offset over LS steps from zero state
  float b0 = 0.f, b1 = 0.f, b2 = 0.f, b3 = 0.f;
  #pragma unroll
  for (int j = 0; j < LS; ++j) {
    float ux = uxp[tid*STR + j], uy = uyp[tid*STR + j];
    float n0, n1, n2, n3;
    STEP4(Mm, Nn, b0, b1, b2, b3, ux, uy, n0, n1, n2, n3);
    b0 = n0; b1 = n1; b2 = n2; b3 = n3;
  }
  S1[tid] = make_float4(b0, b1, b2, b3);
  __syncthreads();

  // in-block Hillis-Steele (8 rounds over 256 offsets)
  #pragma unroll
  for (int k = 0; k < 8; ++k) {
    int off = 1 << k;
    float4 l, c;
    bool act = (tid >= off);
    if (act) { l = S1[tid - off]; c = S1[tid]; }
    __syncthreads();
    if (act) S1[tid] = aff_apply(&SKs[16*k], l, c);
    __syncthreads();
  }

  s1out[bid * BLK + tid] = S1[tid];                  // inclusive prefixes
  if (tid == BLK-1) agg[bid] = S1[BLK-1];            // block aggregate
}

// ---------- pass3: per-block redundant mid-scan + replay + emit (z1,z2) ----------
__launch_bounds__(BLK)
__global__ void k_pass3(const float4* __restrict__ u4, const float* __restrict__ ws,
                        const float4* __restrict__ s1buf, const float4* __restrict__ agg,
                        const float* __restrict__ x0in, float4* __restrict__ out4,
                        int T2, int nblk) {
  __shared__ float  uxp[BLK*STR];
  __shared__ float  uyp[BLK*STR];
  __shared__ float4 MA[512];
  __shared__ float4 MB[512];
  __shared__ float  SKs[8*16];
  __shared__ float  GKs[9*16];
  const int tid   = threadIdx.x;
  const int bid   = blockIdx.x;
  const int base2 = bid * SPB;

  float Mm[16], Nn[8];
  #pragma unroll
  for (int i = 0; i < 16; ++i) Mm[i] = ws[WS_M+i];
  #pragma unroll
  for (int i = 0; i < 8;  ++i) Nn[i] = ws[WS_N+i];
  if (tid < 128) SKs[tid] = ws[WS_SK + tid];
  if (tid < 144) GKs[tid] = ws[WS_GK + tid];

  // stage u
  #pragma unroll
  for (int kk = 0; kk < SPB/2/BLK; ++kk) {
    int idx4 = tid + kk*BLK;
    int s0 = 2*idx4;
    float4 v = make_float4(0.f, 0.f, 0.f, 0.f);
    if (base2 + s0 < T2) v = u4[(base2 >> 1) + idx4];
    int t0 = s0 >> 4, j0 = s0 & 15;
    int t1 = (s0+1) >> 4, j1 = (s0+1) & 15;
    uxp[t0*STR + j0] = v.x;  uyp[t0*STR + j0] = v.y;
    uxp[t1*STR + j1] = v.z;  uyp[t1*STR + j1] = v.w;
  }

  // load [x0, agg_0..agg_{nblk-1}] for the block-local mid scan
  const int n = nblk + 1;
  #pragma unroll
  for (int j = 0; j < 2; ++j) {
    int i = tid + BLK*j;
    if (i < n) MA[i] = (i == 0) ? make_float4(x0in[0], x0in[1], x0in[2], x0in[3])
                                : agg[i-1];
  }
  __syncthreads();

  // ping-pong Hillis-Steele over n<=512 elements (9 rounds)
  float4* Aa = MA; float4* Bb = MB;
  for (int k = 0; k < 9; ++k) {
    int off = 1 << k;
    if (off >= n) break;
    #pragma unroll
    for (int j = 0; j < 2; ++j) {
      int i = tid + BLK*j;
      if (i < n) {
        float4 v = Aa[i];
        if (i >= off) v = aff_apply(&GKs[16*k], Aa[i-off], v);
        Bb[i] = v;
      }
    }
    __syncthreads();
    float4* t = Aa; Aa = Bb; Bb = t;
  }

  float4 Xbs = Aa[bid];   // state at start of this block (LDS broadcast)

  // per-thread start: M^(16*tid)*Xbs (powers commute) + exclusive in-block prefix
  float4 v = Xbs;
  #pragma unroll
  for (int k = 0; k < 8; ++k)
    if (tid & (1 << k)) v = matvec(&SKs[16*k], v);
  float4 p = (tid > 0) ? s1buf[bid*BLK + tid - 1] : make_float4(0.f, 0.f, 0.f, 0.f);
  float x0 = v.x + p.x, x1 = v.y + p.y, x2 = v.z + p.z, x3 = v.w + p.w;

  // replay LS steps, write (z1,z2) back over consumed u planes
  #pragma unroll
  for (int j = 0; j < LS; ++j) {
    float ux = uxp[tid*STR + j], uy = uyp[tid*STR + j];
    float n0, n1, n2, n3;
    STEP4(Mm, Nn, x0, x1, x2, x3, ux, uy, n0, n1, n2, n3);
    x0 = n0; x1 = n1; x2 = n2; x3 = n3;
    uxp[tid*STR + j] = x0;   // z1
    uyp[tid*STR + j] = x2;   // z2
  }
  __syncthreads();

  // coalesced writeout: each float4 = 2 timesteps of (z1,z2)
  #pragma unroll
  for (int kk = 0; kk < SPB/2/BLK; ++kk) {
    int idx4 = tid + kk*BLK;
    int s0 = 2*idx4;
    if (base2 + s0 < T2) {
      int t0 = s0 >> 4, j0 = s0 & 15;
      int t1 = (s0+1) >> 4, j1 = (s0+1) & 15;
      out4[(base2 >> 1) + idx4] = make_float4(uxp[t0*STR + j0], uyp[t0*STR + j0],
                                              uxp[t1*STR + j1], uyp[t1*STR + j1]);
    }
  }
}

extern "C" void kernel_launch(void* const* d_in, const int* in_sizes, int n_in,
                              void* d_out, int out_size, void* d_ws, size_t ws_size,
                              hipStream_t stream) {
  const float* u   = (const float*)d_in[0];
  const float* x0  = (const float*)d_in[1];
  const float* cc  = (const float*)d_in[2];
  const float* mm  = (const float*)d_in[3];
  const float* kk  = (const float*)d_in[4];
  const float* dt  = (const float*)d_in[5];

  const int T2   = in_sizes[0] / 2;            // timesteps
  const int nblk = (T2 + SPB - 1) / SPB;       // 489 for T=2e6; nblk+1 <= 512 required

  float*  ws   = (float*)d_ws;
  float4* agg  = (float4*)(ws + WS_AGG);       // 512 float4 reserved
  float4* s1b  = (float4*)(ws + WS_S1);        // nblk*BLK float4 (~2 MB)

  k_setup<<<1, 1, 0, stream>>>(cc, mm, kk, dt, ws);
  k_pass1<<<nblk, BLK, 0, stream>>>((const float4*)u, ws, s1b, agg, T2);
  k_pass3<<<nblk, BLK, 0, stream>>>((const float4*)u, ws, s1b, agg, x0,
                                    (float4*)d_out, T2, nblk);
}

// Round 5
// 95.323 us; speedup vs baseline: 1.7047x; 1.0335x over previous
//
#include <hip/hip_runtime.h>

#define BLK 256            // threads per block (4 waves)
#define LS  16             // timesteps per thread-chunk
#define SPB (BLK*LS)       // timesteps per block = 4096
#define STR (LS+1)         // plane stride 17: bank=(17t+j)%32, gcd(17,32)=1 -> conflict-free

// ws float offsets: [0) agg (512 float4 = 2048 floats), [2048) S1 buf
#define WS_AGG 0
#define WS_S1  2048

// ---------- affine step macro (row-major M[16], N[8]) ----------
#define STEP4(Mx,Nx, s0,s1,s2,s3, ux,uy, n0,n1,n2,n3)                                              \
  n0 = fmaf(Mx[0],s0,  fmaf(Mx[1],s1,  fmaf(Mx[2],s2,  fmaf(Mx[3],s3,  fmaf(Nx[0],ux, Nx[1]*uy))))); \
  n1 = fmaf(Mx[4],s0,  fmaf(Mx[5],s1,  fmaf(Mx[6],s2,  fmaf(Mx[7],s3,  fmaf(Nx[2],ux, Nx[3]*uy))))); \
  n2 = fmaf(Mx[8],s0,  fmaf(Mx[9],s1,  fmaf(Mx[10],s2, fmaf(Mx[11],s3, fmaf(Nx[4],ux, Nx[5]*uy))))); \
  n3 = fmaf(Mx[12],s0, fmaf(Mx[13],s1, fmaf(Mx[14],s2, fmaf(Mx[15],s3, fmaf(Nx[6],ux, Nx[7]*uy)))));

__device__ __forceinline__ float4 aff_apply(const float* Mx, float4 l, float4 c) {
  float4 r;
  r.x = fmaf(Mx[0],l.x,  fmaf(Mx[1],l.y,  fmaf(Mx[2],l.z,  fmaf(Mx[3],l.w,  c.x))));
  r.y = fmaf(Mx[4],l.x,  fmaf(Mx[5],l.y,  fmaf(Mx[6],l.z,  fmaf(Mx[7],l.w,  c.y))));
  r.z = fmaf(Mx[8],l.x,  fmaf(Mx[9],l.y,  fmaf(Mx[10],l.z, fmaf(Mx[11],l.w, c.z))));
  r.w = fmaf(Mx[12],l.x, fmaf(Mx[13],l.y, fmaf(Mx[14],l.z, fmaf(Mx[15],l.w, c.w))));
  return r;
}

__device__ __forceinline__ float4 matvec(const float* Mx, float4 v) {
  return aff_apply(Mx, v, make_float4(0.f, 0.f, 0.f, 0.f));
}

// ---------- wave-parallel fp64 constant builder (lane (i,j) owns element (i,j)) ----------
// 4x4 matmul element via cross-lane shuffles; no barriers, wave 0 only.
__device__ __forceinline__ double mm_el(double x, double y, int i, int j) {
  double s = 0.0;
  #pragma unroll
  for (int l = 0; l < 4; ++l)
    s = fma(__shfl(x, 4*i + l, 64), __shfl(y, 4*l + j, 64), s);
  return s;
}

__device__ __forceinline__ void wave_setup(const float* __restrict__ cin,
                                           const float* __restrict__ min_,
                                           const float* __restrict__ kin,
                                           const float* __restrict__ dtin,
                                           float* Ms, float* Ns, float* SKs, float* GKs,
                                           int lane, bool wantGK) {
  double c1 = cin[0], c2 = cin[1], c3 = cin[2];
  double m1 = min_[0], m2 = min_[1];
  double k1 = kin[0], k2 = kin[1], k3 = kin[2];
  double h  = dtin[0];
  const int i = (lane >> 2) & 3, j = lane & 3;

  // A element (i,j), no dynamic local-array indexing (avoid scratch)
  double a;
  if (i == 0)      a = (j == 1) ? 1.0 : 0.0;
  else if (i == 2) a = (j == 3) ? 1.0 : 0.0;
  else if (i == 1) a = (j==0) ? -(k1+k2)/m1 : (j==1) ? -(c1+c2)/m1
                     : (j==2) ?  k2/m1      :  c2/m1;
  else             a = (j==0) ?  k2/m2      : (j==1) ?  c2/m2
                     : (j==2) ? -(k3+k2)/m2 : -(c3+c2)/m2;

  const double id = (i == j) ? 1.0 : 0.0;
  double q  = id + (h/4.0)*a;
  double t  = mm_el(a, q,  i, j);
  double r  = id + (h/3.0)*t;
  t         = mm_el(a, r,  i, j);
  double s_ = id + (h/2.0)*t;
  t         = mm_el(a, s_, i, j);
  double m  = id + h*t;
  if (lane < 16) Ms[lane] = (float)m;

  // N[2i'+j'] = h * S[i'][ j' ? 3 : 1 ] / (j' ? m2 : m1), flat e = lane
  {
    int e = lane & 7, ii = e >> 1, jp = e & 1, col = jp ? 3 : 1;
    double sv = __shfl(s_, 4*ii + col, 64);
    double nv = h * sv / (jp ? m2 : m1);
    if (lane < 8) Ns[lane] = (float)nv;
  }

  // P = M^16 (4 squarings); SK[k] = M^(16*2^k), k=0..7
  double p = m;
  #pragma unroll
  for (int rr = 0; rr < 4; ++rr) p = mm_el(p, p, i, j);
  if (lane < 16) SKs[lane] = (float)p;
  #pragma unroll
  for (int k = 1; k < 8; ++k) {
    p = mm_el(p, p, i, j);
    if (lane < 16) SKs[16*k + lane] = (float)p;
  }
  if (wantGK) {
    p = mm_el(p, p, i, j);            // M^4096
    if (lane < 16) GKs[lane] = (float)p;
    #pragma unroll
    for (int k = 1; k < 9; ++k) {     // GK[k] = M^(4096*2^k), k=0..8
      p = mm_el(p, p, i, j);
      if (lane < 16) GKs[16*k + lane] = (float)p;
    }
  }
}

// ---------- pass1: chunk offsets + in-block inclusive scan -> S1 global + aggregate ----------
__launch_bounds__(BLK)
__global__ void k_pass1(const float4* __restrict__ u4,
                        const float* __restrict__ cc, const float* __restrict__ mmp,
                        const float* __restrict__ kp, const float* __restrict__ dtp,
                        float4* __restrict__ s1out, float4* __restrict__ agg, int T2) {
  __shared__ float  uxp[BLK*STR];     // u channel-0 plane, conflict-free stride 17
  __shared__ float  uyp[BLK*STR];     // u channel-1 plane
  __shared__ float4 S1[BLK];
  __shared__ float  Ms[16], Ns[8], SKs[8*16];
  const int tid   = threadIdx.x;
  const int bid   = blockIdx.x;
  const int base2 = bid * SPB;

  // wave 0: build constants in fp64 while waves 1-3 stage u
  if (tid < 64) wave_setup(cc, mmp, kp, dtp, Ms, Ns, SKs, nullptr, tid, false);

  // stage u coalesced into split planes (zeros past T)
  #pragma unroll
  for (int kk = 0; kk < SPB/2/BLK; ++kk) {     // 8 float4 per thread
    int idx4 = tid + kk*BLK;
    int s0 = 2*idx4;
    float4 v = make_float4(0.f, 0.f, 0.f, 0.f);
    if (base2 + s0 < T2) v = u4[(base2 >> 1) + idx4];
    int t0 = s0 >> 4, j0 = s0 & 15;
    int t1 = (s0+1) >> 4, j1 = (s0+1) & 15;
    uxp[t0*STR + j0] = v.x;  uyp[t0*STR + j0] = v.y;
    uxp[t1*STR + j1] = v.z;  uyp[t1*STR + j1] = v.w;
  }
  __syncthreads();

  float Mm[16], Nn[8];
  #pragma unroll
  for (int i = 0; i < 16; ++i) Mm[i] = Ms[i];
  #pragma unroll
  for (int i = 0; i < 8;  ++i) Nn[i] = Ns[i];

  // per-thread chunk offset over LS steps from zero state
  float b0 = 0.f, b1 = 0.f, b2 = 0.f, b3 = 0.f;
  #pragma unroll
  for (int j = 0; j < LS; ++j) {
    float ux = uxp[tid*STR + j], uy = uyp[tid*STR + j];
    float n0, n1, n2, n3;
    STEP4(Mm, Nn, b0, b1, b2, b3, ux, uy, n0, n1, n2, n3);
    b0 = n0; b1 = n1; b2 = n2; b3 = n3;
  }
  S1[tid] = make_float4(b0, b1, b2, b3);
  __syncthreads();

  // in-block Hillis-Steele (8 rounds over 256 offsets)
  #pragma unroll
  for (int k = 0; k < 8; ++k) {
    int off = 1 << k;
    float4 l, c;
    bool act = (tid >= off);
    if (act) { l = S1[tid - off]; c = S1[tid]; }
    __syncthreads();
    if (act) S1[tid] = aff_apply(&SKs[16*k], l, c);
    __syncthreads();
  }

  s1out[bid * BLK + tid] = S1[tid];                  // inclusive prefixes
  if (tid == BLK-1) agg[bid] = S1[BLK-1];            // block aggregate
}

// ---------- pass3: per-block redundant mid-scan + replay + emit (z1,z2) ----------
__launch_bounds__(BLK)
__global__ void k_pass3(const float4* __restrict__ u4,
                        const float* __restrict__ cc, const float* __restrict__ mmp,
                        const float* __restrict__ kp, const float* __restrict__ dtp,
                        const float4* __restrict__ s1buf, const float4* __restrict__ agg,
                        const float* __restrict__ x0in, float4* __restrict__ out4,
                        int T2, int nblk) {
  __shared__ float  uxp[BLK*STR];
  __shared__ float  uyp[BLK*STR];
  __shared__ float4 MA[512];
  __shared__ float4 MB[512];
  __shared__ float  Ms[16], Ns[8], SKs[8*16], GKs[9*16];
  const int tid   = threadIdx.x;
  const int bid   = blockIdx.x;
  const int base2 = bid * SPB;

  if (tid < 64) wave_setup(cc, mmp, kp, dtp, Ms, Ns, SKs, GKs, tid, true);

  // stage u
  #pragma unroll
  for (int kk = 0; kk < SPB/2/BLK; ++kk) {
    int idx4 = tid + kk*BLK;
    int s0 = 2*idx4;
    float4 v = make_float4(0.f, 0.f, 0.f, 0.f);
    if (base2 + s0 < T2) v = u4[(base2 >> 1) + idx4];
    int t0 = s0 >> 4, j0 = s0 & 15;
    int t1 = (s0+1) >> 4, j1 = (s0+1) & 15;
    uxp[t0*STR + j0] = v.x;  uyp[t0*STR + j0] = v.y;
    uxp[t1*STR + j1] = v.z;  uyp[t1*STR + j1] = v.w;
  }

  // load [x0, agg_0..agg_{nblk-1}] for the block-local mid scan
  const int n = nblk + 1;
  #pragma unroll
  for (int j = 0; j < 2; ++j) {
    int i = tid + BLK*j;
    if (i < n) MA[i] = (i == 0) ? make_float4(x0in[0], x0in[1], x0in[2], x0in[3])
                                : agg[i-1];
  }
  __syncthreads();

  float Mm[16], Nn[8];
  #pragma unroll
  for (int i = 0; i < 16; ++i) Mm[i] = Ms[i];
  #pragma unroll
  for (int i = 0; i < 8;  ++i) Nn[i] = Ns[i];

  // ping-pong Hillis-Steele over n<=512 elements (9 rounds)
  float4* Aa = MA; float4* Bb = MB;
  for (int k = 0; k < 9; ++k) {
    int off = 1 << k;
    if (off >= n) break;
    #pragma unroll
    for (int j = 0; j < 2; ++j) {
      int i = tid + BLK*j;
      if (i < n) {
        float4 v = Aa[i];
        if (i >= off) v = aff_apply(&GKs[16*k], Aa[i-off], v);
        Bb[i] = v;
      }
    }
    __syncthreads();
    float4* t = Aa; Aa = Bb; Bb = t;
  }

  float4 Xbs = Aa[bid];   // state at start of this block (LDS broadcast)

  // per-thread start: M^(16*tid)*Xbs (powers commute) + exclusive in-block prefix
  float4 v = Xbs;
  #pragma unroll
  for (int k = 0; k < 8; ++k)
    if (tid & (1 << k)) v = matvec(&SKs[16*k], v);
  float4 p = (tid > 0) ? s1buf[bid*BLK + tid - 1] : make_float4(0.f, 0.f, 0.f, 0.f);
  float x0 = v.x + p.x, x1 = v.y + p.y, x2 = v.z + p.z, x3 = v.w + p.w;

  // replay LS steps, write (z1,z2) back over consumed u planes
  #pragma unroll
  for (int j = 0; j < LS; ++j) {
    float ux = uxp[tid*STR + j], uy = uyp[tid*STR + j];
    float n0, n1, n2, n3;
    STEP4(Mm, Nn, x0, x1, x2, x3, ux, uy, n0, n1, n2, n3);
    x0 = n0; x1 = n1; x2 = n2; x3 = n3;
    uxp[tid*STR + j] = x0;   // z1
    uyp[tid*STR + j] = x2;   // z2
  }
  __syncthreads();

  // coalesced writeout: each float4 = 2 timesteps of (z1,z2)
  #pragma unroll
  for (int kk = 0; kk < SPB/2/BLK; ++kk) {
    int idx4 = tid + kk*BLK;
    int s0 = 2*idx4;
    if (base2 + s0 < T2) {
      int t0 = s0 >> 4, j0 = s0 & 15;
      int t1 = (s0+1) >> 4, j1 = (s0+1) & 15;
      out4[(base2 >> 1) + idx4] = make_float4(uxp[t0*STR + j0], uyp[t0*STR + j0],
                                              uxp[t1*STR + j1], uyp[t1*STR + j1]);
    }
  }
}

extern "C" void kernel_launch(void* const* d_in, const int* in_sizes, int n_in,
                              void* d_out, int out_size, void* d_ws, size_t ws_size,
                              hipStream_t stream) {
  const float* u   = (const float*)d_in[0];
  const float* x0  = (const float*)d_in[1];
  const float* cc  = (const float*)d_in[2];
  const float* mm  = (const float*)d_in[3];
  const float* kk  = (const float*)d_in[4];
  const float* dt  = (const float*)d_in[5];

  const int T2   = in_sizes[0] / 2;            // timesteps
  const int nblk = (T2 + SPB - 1) / SPB;       // 489 for T=2e6; nblk+1 <= 512 required

  float*  ws  = (float*)d_ws;
  float4* agg = (float4*)(ws + WS_AGG);        // 512 float4 reserved
  float4* s1b = (float4*)(ws + WS_S1);         // nblk*BLK float4 (~2 MB)

  k_pass1<<<nblk, BLK, 0, stream>>>((const float4*)u, cc, mm, kk, dt, s1b, agg, T2);
  k_pass3<<<nblk, BLK, 0, stream>>>((const float4*)u, cc, mm, kk, dt, s1b, agg, x0,
                                    (float4*)d_out, T2, nblk);
}

// Round 7
// 94.865 us; speedup vs baseline: 1.7129x; 1.0048x over previous
//
#include <hip/hip_runtime.h>

#define BLK 256            // threads per block (4 waves)
#define LS  16             // timesteps per thread-chunk
#define SPB (BLK*LS)       // timesteps per block = 4096
#define STR (LS+1)         // plane stride 17: bank=(17t+j)%32, gcd(17,32)=1 -> conflict-free

// ws float layout: [0:296) constants (M 16, N 8, SK 128, GK 144), [320) agg (512 float4)
#define WC_M   0
#define WC_N   16
#define WC_SK  24
#define WC_GK  152
#define WC_TOT 296
#define WS_AGG 320

// ---------- affine step macro (row-major M[16], N[8]) ----------
#define STEP4(Mx,Nx, s0,s1,s2,s3, ux,uy, n0,n1,n2,n3)                                              \
  n0 = fmaf(Mx[0],s0,  fmaf(Mx[1],s1,  fmaf(Mx[2],s2,  fmaf(Mx[3],s3,  fmaf(Nx[0],ux, Nx[1]*uy))))); \
  n1 = fmaf(Mx[4],s0,  fmaf(Mx[5],s1,  fmaf(Mx[6],s2,  fmaf(Mx[7],s3,  fmaf(Nx[2],ux, Nx[3]*uy))))); \
  n2 = fmaf(Mx[8],s0,  fmaf(Mx[9],s1,  fmaf(Mx[10],s2, fmaf(Mx[11],s3, fmaf(Nx[4],ux, Nx[5]*uy))))); \
  n3 = fmaf(Mx[12],s0, fmaf(Mx[13],s1, fmaf(Mx[14],s2, fmaf(Mx[15],s3, fmaf(Nx[6],ux, Nx[7]*uy)))));

__device__ __forceinline__ float4 aff_apply(const float* Mx, float4 l, float4 c) {
  float4 r;
  r.x = fmaf(Mx[0],l.x,  fmaf(Mx[1],l.y,  fmaf(Mx[2],l.z,  fmaf(Mx[3],l.w,  c.x))));
  r.y = fmaf(Mx[4],l.x,  fmaf(Mx[5],l.y,  fmaf(Mx[6],l.z,  fmaf(Mx[7],l.w,  c.y))));
  r.z = fmaf(Mx[8],l.x,  fmaf(Mx[9],l.y,  fmaf(Mx[10],l.z, fmaf(Mx[11],l.w, c.z))));
  r.w = fmaf(Mx[12],l.x, fmaf(Mx[13],l.y, fmaf(Mx[14],l.z, fmaf(Mx[15],l.w, c.w))));
  return r;
}

__device__ __forceinline__ float4 matvec(const float* Mx, float4 v) {
  return aff_apply(Mx, v, make_float4(0.f, 0.f, 0.f, 0.f));
}

__device__ __forceinline__ float4 shfl_up4(float4 v, int d) {
  return make_float4(__shfl_up(v.x, d, 64), __shfl_up(v.y, d, 64),
                     __shfl_up(v.z, d, 64), __shfl_up(v.w, d, 64));
}

// ---------- wave-parallel fp64 constant builder (lane (i,j) owns element (i,j)) ----------
__device__ __forceinline__ double mm_el(double x, double y, int i, int j) {
  double s = 0.0;
  #pragma unroll
  for (int l = 0; l < 4; ++l)
    s = fma(__shfl(x, 4*i + l, 64), __shfl(y, 4*l + j, 64), s);
  return s;
}

__device__ __forceinline__ void wave_setup(const float* __restrict__ cin,
                                           const float* __restrict__ min_,
                                           const float* __restrict__ kin,
                                           const float* __restrict__ dtin,
                                           float* C, int lane, bool wantGK) {
  double c1 = cin[0], c2 = cin[1], c3 = cin[2];
  double m1 = min_[0], m2 = min_[1];
  double k1 = kin[0], k2 = kin[1], k3 = kin[2];
  double h  = dtin[0];
  const int i = (lane >> 2) & 3, j = lane & 3;

  double a;
  if (i == 0)      a = (j == 1) ? 1.0 : 0.0;
  else if (i == 2) a = (j == 3) ? 1.0 : 0.0;
  else if (i == 1) a = (j==0) ? -(k1+k2)/m1 : (j==1) ? -(c1+c2)/m1
                     : (j==2) ?  k2/m1      :  c2/m1;
  else             a = (j==0) ?  k2/m2      : (j==1) ?  c2/m2
                     : (j==2) ? -(k3+k2)/m2 : -(c3+c2)/m2;

  const double id = (i == j) ? 1.0 : 0.0;
  double q  = id + (h/4.0)*a;
  double t  = mm_el(a, q,  i, j);
  double r  = id + (h/3.0)*t;
  t         = mm_el(a, r,  i, j);
  double s_ = id + (h/2.0)*t;
  t         = mm_el(a, s_, i, j);
  double m  = id + h*t;
  if (lane < 16) C[WC_M + lane] = (float)m;

  {
    int e = lane & 7, ii = e >> 1, jp = e & 1, col = jp ? 3 : 1;
    double sv = __shfl(s_, 4*ii + col, 64);
    double nv = h * sv / (jp ? m2 : m1);
    if (lane < 8) C[WC_N + lane] = (float)nv;
  }

  // P = M^16; SK[k] = M^(16*2^k), k=0..7
  double p = m;
  #pragma unroll
  for (int rr = 0; rr < 4; ++rr) p = mm_el(p, p, i, j);
  if (lane < 16) C[WC_SK + lane] = (float)p;
  #pragma unroll
  for (int k = 1; k < 8; ++k) {
    p = mm_el(p, p, i, j);
    if (lane < 16) C[WC_SK + 16*k + lane] = (float)p;
  }
  if (wantGK) {
    p = mm_el(p, p, i, j);            // M^4096
    if (lane < 16) C[WC_GK + lane] = (float)p;
    #pragma unroll
    for (int k = 1; k < 9; ++k) {     // GK[k] = M^(4096*2^k)
      p = mm_el(p, p, i, j);
      if (lane < 16) C[WC_GK + 16*k + lane] = (float)p;
    }
  }
}

// ---------- shared building blocks ----------
// Wave-level inclusive affine scan over 64 chunk offsets (no barriers).
__device__ __forceinline__ float4 wave_scan(const float* SK, float4 b, int lane) {
  float4 cur = b;
  #pragma unroll
  for (int k = 0; k < 6; ++k) {
    int off = 1 << k;
    float4 l  = shfl_up4(cur, off);
    float4 nv = aff_apply(&SK[16*k], l, cur);
    if (lane >= off) cur = nv;
  }
  return cur;
}

// Cross-wave exclusive offset E_w = composed offset of waves 0..w-1 (each 1024 steps).
__device__ __forceinline__ float4 cross_wave_excl(const float* SK, const float4* Wagg, int w) {
  float4 E = make_float4(0.f, 0.f, 0.f, 0.f);
  if (w > 0) {
    E = Wagg[0];
    for (int q = 1; q < w; ++q) E = aff_apply(&SK[16*6], E, Wagg[q]);  // SK6 = M^1024
  }
  return E;
}

// ---------- pass1: chunk offsets + block scan -> block aggregate (+ consts from block 0) ----------
__launch_bounds__(BLK)
__global__ void k_pass1(const float4* __restrict__ u4,
                        const float* __restrict__ cc, const float* __restrict__ mmp,
                        const float* __restrict__ kp, const float* __restrict__ dtp,
                        float* __restrict__ wsc, float4* __restrict__ agg, int T2) {
  __shared__ float  uxp[BLK*STR];
  __shared__ float  uyp[BLK*STR];
  __shared__ float  C[WC_TOT];
  __shared__ float4 Wagg[4];
  const int tid   = threadIdx.x;
  const int bid   = blockIdx.x;
  const int lane  = tid & 63, w = tid >> 6;
  const int base2 = bid * SPB;

  // wave 0 builds constants in fp64 (block 0 also GK) while waves 1-3 stage u
  if (tid < 64) wave_setup(cc, mmp, kp, dtp, C, tid, bid == 0);

  #pragma unroll
  for (int kk = 0; kk < SPB/2/BLK; ++kk) {
    int idx4 = tid + kk*BLK;
    int s0 = 2*idx4;
    float4 v = make_float4(0.f, 0.f, 0.f, 0.f);
    if (base2 + s0 < T2) v = u4[(base2 >> 1) + idx4];
    int t0 = s0 >> 4, j0 = s0 & 15;
    int t1 = (s0+1) >> 4, j1 = (s0+1) & 15;
    uxp[t0*STR + j0] = v.x;  uyp[t0*STR + j0] = v.y;
    uxp[t1*STR + j1] = v.z;  uyp[t1*STR + j1] = v.w;
  }
  __syncthreads();

  // block 0 publishes constants for pass3
  if (bid == 0)
    for (int i = tid; i < WC_TOT; i += BLK) wsc[i] = C[i];

  float Mm[16], Nn[8];
  #pragma unroll
  for (int i = 0; i < 16; ++i) Mm[i] = C[WC_M+i];
  #pragma unroll
  for (int i = 0; i < 8;  ++i) Nn[i] = C[WC_N+i];
  const float* SK = &C[WC_SK];

  // per-thread chunk offset over LS steps from zero state
  float b0 = 0.f, b1 = 0.f, b2 = 0.f, b3 = 0.f;
  #pragma unroll
  for (int j = 0; j < LS; ++j) {
    float ux = uxp[tid*STR + j], uy = uyp[tid*STR + j];
    float n0, n1, n2, n3;
    STEP4(Mm, Nn, b0, b1, b2, b3, ux, uy, n0, n1, n2, n3);
    b0 = n0; b1 = n1; b2 = n2; b3 = n3;
  }

  float4 incl = wave_scan(SK, make_float4(b0, b1, b2, b3), lane);
  if (lane == 63) Wagg[w] = incl;
  __syncthreads();

  if (tid == BLK-1) {
    // block aggregate = M^1024 * E_3 + wave-3 inclusive
    float4 E = cross_wave_excl(SK, Wagg, 3);
    float4 t_ = matvec(&SK[16*6], E);
    agg[bid] = make_float4(incl.x + t_.x, incl.y + t_.y, incl.z + t_.z, incl.w + t_.w);
  }
}

// ---------- pass3: mid-scan + recomputed offsets + replay + emit (z1,z2) ----------
__launch_bounds__(BLK)
__global__ void k_pass3(const float4* __restrict__ u4,
                        const float* __restrict__ wsc,
                        const float4* __restrict__ agg,
                        const float* __restrict__ x0in, float4* __restrict__ out4,
                        int T2, int nblk) {
  __shared__ float  uxp[BLK*STR];
  __shared__ float  uyp[BLK*STR];
  __shared__ float4 MA[512];
  __shared__ float4 MB[512];
  __shared__ float  C[WC_TOT];
  __shared__ float4 Wagg[4];
  const int tid   = threadIdx.x;
  const int bid   = blockIdx.x;
  const int lane  = tid & 63, w = tid >> 6;
  const int base2 = bid * SPB;

  // load constants (written by pass1 block 0)
  for (int i = tid; i < WC_TOT; i += BLK) C[i] = wsc[i];

  // stage u
  #pragma unroll
  for (int kk = 0; kk < SPB/2/BLK; ++kk) {
    int idx4 = tid + kk*BLK;
    int s0 = 2*idx4;
    float4 v = make_float4(0.f, 0.f, 0.f, 0.f);
    if (base2 + s0 < T2) v = u4[(base2 >> 1) + idx4];
    int t0 = s0 >> 4, j0 = s0 & 15;
    int t1 = (s0+1) >> 4, j1 = (s0+1) & 15;
    uxp[t0*STR + j0] = v.x;  uyp[t0*STR + j0] = v.y;
    uxp[t1*STR + j1] = v.z;  uyp[t1*STR + j1] = v.w;
  }

  // load [x0, agg_0..agg_{nblk-1}] for the block-local mid scan
  const int n = nblk + 1;
  #pragma unroll
  for (int j = 0; j < 2; ++j) {
    int i = tid + BLK*j;
    if (i < n) MA[i] = (i == 0) ? make_float4(x0in[0], x0in[1], x0in[2], x0in[3])
                                : agg[i-1];
  }
  __syncthreads();

  float Mm[16], Nn[8];
  #pragma unroll
  for (int i = 0; i < 16; ++i) Mm[i] = C[WC_M+i];
  #pragma unroll
  for (int i = 0; i < 8;  ++i) Nn[i] = C[WC_N+i];
  const float* SK = &C[WC_SK];
  const float* GK = &C[WC_GK];

  // per-thread chunk offset (recomputed; saves the s1buf round-trip)
  float b0 = 0.f, b1 = 0.f, b2 = 0.f, b3 = 0.f;
  #pragma unroll
  for (int j = 0; j < LS; ++j) {
    float ux = uxp[tid*STR + j], uy = uyp[tid*STR + j];
    float n0, n1, n2, n3;
    STEP4(Mm, Nn, b0, b1, b2, b3, ux, uy, n0, n1, n2, n3);
    b0 = n0; b1 = n1; b2 = n2; b3 = n3;
  }
  float4 incl = wave_scan(SK, make_float4(b0, b1, b2, b3), lane);
  if (lane == 63) Wagg[w] = incl;
  // (visibility of Wagg provided by the mid-scan's barriers below)

  // ping-pong Hillis-Steele mid scan over n<=512 elements (9 rounds, 1 sync each)
  float4* Aa = MA; float4* Bb = MB;
  for (int k = 0; k < 9; ++k) {
    int off = 1 << k;
    if (off >= n) break;
    #pragma unroll
    for (int j = 0; j < 2; ++j) {
      int i = tid + BLK*j;
      if (i < n) {
        float4 v = Aa[i];
        if (i >= off) v = aff_apply(&GK[16*k], Aa[i-off], v);
        Bb[i] = v;
      }
    }
    __syncthreads();
    float4* t = Aa; Aa = Bb; Bb = t;
  }

  float4 Xbs = Aa[bid];                       // state at start of this block

  // ---- FIX (round 6 bug): wave-start state, then per-lane start ----
  // X_w = M^(1024*w)*Xbs + E_w   (E_w = composed offset of waves 0..w-1)
  float4 E  = cross_wave_excl(SK, Wagg, w);
  float4 Xw = Xbs;
  if (w & 1) Xw = matvec(&SK[16*6], Xw);      // M^1024
  if (w & 2) Xw = matvec(&SK[16*7], Xw);      // M^2048
  Xw = make_float4(Xw.x + E.x, Xw.y + E.y, Xw.z + E.z, Xw.w + E.w);

  // start = M^(16*lane)*X_w + (lane>0 ? incl[lane-1] : 0)
  float4 ex = shfl_up4(incl, 1);
  if (lane == 0) ex = make_float4(0.f, 0.f, 0.f, 0.f);
  float4 v = Xw;
  #pragma unroll
  for (int k = 0; k < 6; ++k)
    if (lane & (1 << k)) v = matvec(&SK[16*k], v);   // powers of M commute
  float x0 = v.x + ex.x, x1 = v.y + ex.y, x2 = v.z + ex.z, x3 = v.w + ex.w;

  // replay LS steps, write (z1,z2) back over consumed u planes
  #pragma unroll
  for (int j = 0; j < LS; ++j) {
    float ux = uxp[tid*STR + j], uy = uyp[tid*STR + j];
    float n0, n1, n2, n3;
    STEP4(Mm, Nn, x0, x1, x2, x3, ux, uy, n0, n1, n2, n3);
    x0 = n0; x1 = n1; x2 = n2; x3 = n3;
    uxp[tid*STR + j] = x0;   // z1
    uyp[tid*STR + j] = x2;   // z2
  }
  __syncthreads();

  // coalesced writeout: each float4 = 2 timesteps of (z1,z2)
  #pragma unroll
  for (int kk = 0; kk < SPB/2/BLK; ++kk) {
    int idx4 = tid + kk*BLK;
    int s0 = 2*idx4;
    if (base2 + s0 < T2) {
      int t0 = s0 >> 4, j0 = s0 & 15;
      int t1 = (s0+1) >> 4, j1 = (s0+1) & 15;
      out4[(base2 >> 1) + idx4] = make_float4(uxp[t0*STR + j0], uyp[t0*STR + j0],
                                              uxp[t1*STR + j1], uyp[t1*STR + j1]);
    }
  }
}

extern "C" void kernel_launch(void* const* d_in, const int* in_sizes, int n_in,
                              void* d_out, int out_size, void* d_ws, size_t ws_size,
                              hipStream_t stream) {
  const float* u   = (const float*)d_in[0];
  const float* x0  = (const float*)d_in[1];
  const float* cc  = (const float*)d_in[2];
  const float* mm  = (const float*)d_in[3];
  const float* kk  = (const float*)d_in[4];
  const float* dt  = (const float*)d_in[5];

  const int T2   = in_sizes[0] / 2;            // timesteps
  const int nblk = (T2 + SPB - 1) / SPB;       // 489 for T=2e6; nblk+1 <= 512 required

  float*  ws  = (float*)d_ws;
  float4* agg = (float4*)(ws + WS_AGG);        // 512 float4 reserved

  k_pass1<<<nblk, BLK, 0, stream>>>((const float4*)u, cc, mm, kk, dt, ws, agg, T2);
  k_pass3<<<nblk, BLK, 0, stream>>>((const float4*)u, ws, agg, x0,
                                    (float4*)d_out, T2, nblk);
}